// Round 1
// baseline (41.936 us; speedup 1.0000x reference)
//
#include <hip/hip_runtime.h>
#include <math.h>

#define NBATCH 8192
#define NIN 64
#define NOUT 64
#define NG 17

// d_out layout (flat, f32): output[8192*64] | edge[8192*64*64] | basis[8192*64*17]
#define OUT_ELEMS   (NBATCH * NOUT)
#define EDGE_ELEMS  (NBATCH * NIN * NOUT)
#define BASIS_ELEMS (NBATCH * NIN * NG)
#define WT_BYTES    (NIN * NG * NOUT * sizeof(float))

// Transpose spline_weight [in][out][grid] -> [in][grid][out] so per-(i,g) rows
// are coalesced 64-float vectors.
__global__ void kan_transpose_w(const float* __restrict__ W, float* __restrict__ Wt) {
    int idx = blockIdx.x * blockDim.x + threadIdx.x;
    if (idx >= NIN * NOUT * NG) return;
    int i   = idx / (NOUT * NG);
    int rem = idx - i * (NOUT * NG);
    int o   = rem / NG;
    int g   = rem - o * NG;
    Wt[(i * NG + g) * NOUT + o] = W[idx];
}

// One wave (64 lanes) per batch row; block = 4 waves = 4 rows.
template <bool USE_WT>
__global__ __launch_bounds__(256) void kan_kernel(
    const float* __restrict__ x,      // [B, 64]
    const float* __restrict__ scale,  // [64, 64]
    const float* __restrict__ W,      // [64, 64, 17] (original)
    const float* __restrict__ Wt,     // [64, 17, 64] (transposed, may be null)
    const float* __restrict__ bias,   // [64]
    float* __restrict__ out,          // [B, 64]
    float* __restrict__ edge,         // [B, 64, 64]
    float* __restrict__ basis)        // [B, 64, 17]
{
    const int wave = threadIdx.x >> 6;
    const int lane = threadIdx.x & 63;
    const int b = blockIdx.x * 4 + wave;

    __shared__ float s_silu[4][64];
    __shared__ float s_t[4][64];
    __shared__ int   s_g0[4][64];

    // ---- phase 1: per-input-feature precompute (lane == i) ----
    {
        float xv  = x[b * NIN + lane];
        float sig = 1.0f / (1.0f + __expf(-xv));
        s_silu[wave][lane] = xv * sig;
        // u = (x - grid_lo) / spacing ; spacing = 5/16 = 0.3125 (exact)
        float u   = (xv + 2.5f) * 3.2f;
        float g0f = floorf(u);
        s_t[wave][lane]  = u - g0f;      // in [0,1)
        s_g0[wave][lane] = (int)g0f;     // may be out of [0,17) for tail x
    }
    __syncthreads();

    // ---- phase 2: basis writes, fully coalesced (17 floats/lane) ----
    {
        float* brow = basis + (size_t)b * (NIN * NG);
        #pragma unroll
        for (int k = 0; k < NG; ++k) {
            int p = k * 64 + lane;               // 0..1087, contiguous per store
            int i = (int)((unsigned)p / 17u);    // compiler -> magic mul
            int g = p - i * 17;
            int   g0 = s_g0[wave][i];
            float t  = s_t[wave][i];
            float v  = (g == g0) ? (1.0f - t) : ((g == g0 + 1) ? t : 0.0f);
            brow[p] = v;
        }
    }

    // ---- phase 3: edge outputs + per-row reduction (lane == o) ----
    float acc = 0.0f;
    float* erow = edge + (size_t)b * (NIN * NOUT);
    #pragma unroll 4
    for (int i = 0; i < NIN; ++i) {
        float sl = s_silu[wave][i];
        float t  = s_t[wave][i];
        int   g0 = s_g0[wave][i];      // wave-uniform
        float w0 = 0.0f, w1 = 0.0f;
        if (USE_WT) {
            if (g0 >= 0 && g0 < NG)         w0 = Wt[(i * NG + g0) * NOUT + lane];
            if (g0 + 1 >= 0 && g0 + 1 < NG) w1 = Wt[(i * NG + g0 + 1) * NOUT + lane];
        } else {
            if (g0 >= 0 && g0 < NG)         w0 = W[(i * NOUT + lane) * NG + g0];
            if (g0 + 1 >= 0 && g0 + 1 < NG) w1 = W[(i * NOUT + lane) * NG + g0 + 1];
        }
        float v = sl * scale[i * NOUT + lane] + (1.0f - t) * w0 + t * w1;
        erow[i * NOUT + lane] = v;
        acc += v;
    }
    out[b * NOUT + lane] = acc * 0.125f + bias[lane];   // 1/sqrt(64) = 0.125 exact
}

extern "C" void kernel_launch(void* const* d_in, const int* in_sizes, int n_in,
                              void* d_out, int out_size, void* d_ws, size_t ws_size,
                              hipStream_t stream) {
    const float* x     = (const float*)d_in[0];
    const float* scale = (const float*)d_in[1];
    const float* W     = (const float*)d_in[2];
    const float* bias  = (const float*)d_in[3];

    float* out   = (float*)d_out;
    float* edge  = out + OUT_ELEMS;
    float* basis = edge + EDGE_ELEMS;

    const int rows_per_block = 4;
    dim3 grid(NBATCH / rows_per_block);
    dim3 block(256);

    if (ws_size >= WT_BYTES) {
        float* Wt = (float*)d_ws;
        int n = NIN * NOUT * NG;
        kan_transpose_w<<<(n + 255) / 256, 256, 0, stream>>>(W, Wt);
        kan_kernel<true><<<grid, block, 0, stream>>>(x, scale, W, Wt, bias, out, edge, basis);
    } else {
        kan_kernel<false><<<grid, block, 0, stream>>>(x, scale, W, nullptr, bias, out, edge, basis);
    }
}

// Round 6
// 40.731 us; speedup vs baseline: 1.0296x; 1.0296x over previous
//
#include <hip/hip_runtime.h>
#include <math.h>

#define NBATCH 8192
#define NIN 64
#define NOUT 64
#define NG 17

typedef float f32x4 __attribute__((ext_vector_type(4)));

// d_out layout (flat, f32): output[8192*64] | edge[8192*64*64] | basis[8192*64*17]
#define OUT_ELEMS   (NBATCH * NOUT)
#define EDGE_ELEMS  (NBATCH * NIN * NOUT)
#define WT_BYTES    (NIN * NG * NOUT * sizeof(float))

// Transpose spline_weight [in][out][grid] -> [in][grid][out] so per-(i,g) rows
// are coalesced 64-float vectors.
__global__ void kan_transpose_w(const float* __restrict__ W, float* __restrict__ Wt) {
    int idx = blockIdx.x * blockDim.x + threadIdx.x;
    if (idx >= NIN * NOUT * NG) return;
    int i   = idx / (NOUT * NG);
    int rem = idx - i * (NOUT * NG);
    int o   = rem / NG;
    int g   = rem - o * NG;
    Wt[(i * NG + g) * NOUT + o] = W[idx];
}

// One wave (64 lanes) per batch row; block = 4 waves = 4 rows.
__global__ __launch_bounds__(256) void kan_kernel(
    const float* __restrict__ x,      // [B, 64]
    const float* __restrict__ scale,  // [64, 64]
    const float* __restrict__ Wt,     // [64, 17, 64] (transposed)
    const float* __restrict__ bias,   // [64]
    float* __restrict__ out,          // [B, 64]
    float* __restrict__ edge,         // [B, 64, 64]
    float* __restrict__ basis)        // [B, 64, 17]
{
    const int wave = threadIdx.x >> 6;
    const int lane = threadIdx.x & 63;
    const int b = blockIdx.x * 4 + wave;

    __shared__ float s_silu[4][64];
    __shared__ float s_t[4][64];
    __shared__ int   s_g0[4][64];

    // ---- phase 1: per-input-feature precompute (lane == i) ----
    {
        float xv  = x[b * NIN + lane];
        float sig = 1.0f / (1.0f + __expf(-xv));
        s_silu[wave][lane] = xv * sig;
        // u = (x - grid_lo) / spacing ; spacing = 5/16 = 0.3125 exact; 1/h = 3.2
        float u   = (xv + 2.5f) * 3.2f;
        float g0f = floorf(u);
        s_t[wave][lane]  = u - g0f;      // in [0,1)
        s_g0[wave][lane] = (int)g0f;     // may be out of [0,17) for tail x
    }
    __syncthreads();

    // ---- phase 2: basis writes, float4-vectorized (1088 floats = 272 f4) ----
    {
        float* brow = basis + (size_t)b * (NIN * NG);
        #pragma unroll
        for (int k = 0; k < 4; ++k) {
            int p0 = (k * 64 + lane) * 4;          // element base, 16B aligned
            f32x4 v;
            #pragma unroll
            for (int e = 0; e < 4; ++e) {
                int p = p0 + e;
                int i = (int)((unsigned)p / 17u);  // magic mul
                int g = p - i * 17;
                int   g0 = s_g0[wave][i];
                float t  = s_t[wave][i];
                v[e] = (g == g0) ? (1.0f - t) : ((g == g0 + 1) ? t : 0.0f);
            }
            __builtin_nontemporal_store(v, (f32x4*)(brow + p0));
        }
        if (lane < 16) {                           // tail: f4 indices 256..271
            int p0 = (256 + lane) * 4;
            f32x4 v;
            #pragma unroll
            for (int e = 0; e < 4; ++e) {
                int p = p0 + e;
                int i = (int)((unsigned)p / 17u);
                int g = p - i * 17;
                int   g0 = s_g0[wave][i];
                float t  = s_t[wave][i];
                v[e] = (g == g0) ? (1.0f - t) : ((g == g0 + 1) ? t : 0.0f);
            }
            __builtin_nontemporal_store(v, (f32x4*)(brow + p0));
        }
    }

    // ---- phase 3: edge outputs (float4) + per-row reduction ----
    // Lane layout: quarter iq = lane>>4 owns input i = ib+iq; o = (lane&15)*4.
    f32x4 acc = {0.f, 0.f, 0.f, 0.f};
    float* erow = edge + (size_t)b * (NIN * NOUT);
    const int iq = lane >> 4;
    const int o  = (lane & 15) * 4;
    #pragma unroll 4
    for (int ib = 0; ib < NIN; ib += 4) {
        int   i  = ib + iq;
        float sl = s_silu[wave][i];
        float t  = s_t[wave][i];
        int   g0 = s_g0[wave][i];
        f32x4 sc = *(const f32x4*)(scale + i * NOUT + o);
        f32x4 w0 = {0.f, 0.f, 0.f, 0.f};
        f32x4 w1 = {0.f, 0.f, 0.f, 0.f};
        if ((unsigned)g0       < (unsigned)NG) w0 = *(const f32x4*)(Wt + (i * NG + g0)     * NOUT + o);
        if ((unsigned)(g0 + 1) < (unsigned)NG) w1 = *(const f32x4*)(Wt + (i * NG + g0 + 1) * NOUT + o);
        float mt = 1.0f - t;
        f32x4 v = sl * sc + mt * w0 + t * w1;
        __builtin_nontemporal_store(v, (f32x4*)(erow + i * NOUT + o));
        acc += v;
    }
    // sum across the 4 quarters (lanes differing in bits 4,5)
    #pragma unroll
    for (int e = 0; e < 4; ++e) {
        float a = acc[e];
        a += __shfl_xor(a, 16);
        a += __shfl_xor(a, 32);
        acc[e] = a;
    }
    if (lane < 16) {
        f32x4 bi = *(const f32x4*)(bias + lane * 4);
        f32x4 r = acc * 0.125f + bi;   // 1/sqrt(64) = 0.125 exact
        *(f32x4*)(out + (size_t)b * NOUT + lane * 4) = r;
    }
}

extern "C" void kernel_launch(void* const* d_in, const int* in_sizes, int n_in,
                              void* d_out, int out_size, void* d_ws, size_t ws_size,
                              hipStream_t stream) {
    const float* x     = (const float*)d_in[0];
    const float* scale = (const float*)d_in[1];
    const float* W     = (const float*)d_in[2];
    const float* bias  = (const float*)d_in[3];

    float* out   = (float*)d_out;
    float* edge  = out + OUT_ELEMS;
    float* basis = edge + EDGE_ELEMS;

    float* Wt = (float*)d_ws;
    const int n = NIN * NOUT * NG;
    if (ws_size >= WT_BYTES) {
        kan_transpose_w<<<(n + 255) / 256, 256, 0, stream>>>(W, Wt);
        kan_kernel<<<dim3(NBATCH / 4), dim3(256), 0, stream>>>(x, scale, Wt, bias, out, edge, basis);
    }
}

// Round 7
// 39.091 us; speedup vs baseline: 1.0728x; 1.0419x over previous
//
#include <hip/hip_runtime.h>
#include <math.h>

#define NBATCH 8192
#define NIN 64
#define NOUT 64
#define NG 17

typedef float f32x4 __attribute__((ext_vector_type(4)));

// d_out layout (flat, f32): output[8192*64] | edge[8192*64*64] | basis[8192*64*17]
#define OUT_ELEMS   (NBATCH * NOUT)
#define EDGE_ELEMS  (NBATCH * NIN * NOUT)
#define WT_BYTES    (NIN * NG * NOUT * sizeof(float))

// Transpose spline_weight [in][out][grid] -> [in][grid][out] so per-(i,g) rows
// are coalesced 64-float vectors.
__global__ void kan_transpose_w(const float* __restrict__ W, float* __restrict__ Wt) {
    int idx = blockIdx.x * blockDim.x + threadIdx.x;
    if (idx >= NIN * NOUT * NG) return;
    int i   = idx / (NOUT * NG);
    int rem = idx - i * (NOUT * NG);
    int o   = rem / NG;
    int g   = rem - o * NG;
    Wt[(i * NG + g) * NOUT + o] = W[idx];
}

// One wave (64 lanes) per batch row; block = 4 waves = 4 rows.
__global__ __launch_bounds__(256) void kan_kernel(
    const float* __restrict__ x,      // [B, 64]
    const float* __restrict__ scale,  // [64, 64]
    const float* __restrict__ Wt,     // [64, 17, 64] (transposed)
    const float* __restrict__ bias,   // [64]
    float* __restrict__ out,          // [B, 64]
    float* __restrict__ edge,         // [B, 64, 64]
    float* __restrict__ basis)        // [B, 64, 17]
{
    const int wave = threadIdx.x >> 6;
    const int lane = threadIdx.x & 63;
    const int b = blockIdx.x * 4 + wave;

    __shared__ float s_silu[4][64];
    __shared__ float s_t[4][64];
    __shared__ int   s_g0[4][64];

    // ---- phase 1: per-input-feature precompute (lane == i) ----
    {
        float xv  = x[b * NIN + lane];
        float sig = 1.0f / (1.0f + __expf(-xv));
        s_silu[wave][lane] = xv * sig;
        // u = (x - grid_lo) / spacing ; spacing = 5/16 = 0.3125 exact; 1/h = 3.2
        float u   = (xv + 2.5f) * 3.2f;
        float g0f = floorf(u);
        s_t[wave][lane]  = u - g0f;      // in [0,1)
        s_g0[wave][lane] = (int)g0f;     // may be out of [0,17) for tail x
    }
    __syncthreads();

    // ---- phase 2: basis writes, float4-vectorized (1088 floats = 272 f4) ----
    {
        float* brow = basis + (size_t)b * (NIN * NG);
        #pragma unroll
        for (int k = 0; k < 4; ++k) {
            int p0 = (k * 64 + lane) * 4;          // element base, 16B aligned
            f32x4 v;
            #pragma unroll
            for (int e = 0; e < 4; ++e) {
                int p = p0 + e;
                int i = (int)((unsigned)p / 17u);  // magic mul
                int g = p - i * 17;
                int   g0 = s_g0[wave][i];
                float t  = s_t[wave][i];
                v[e] = (g == g0) ? (1.0f - t) : ((g == g0 + 1) ? t : 0.0f);
            }
            *(f32x4*)(brow + p0) = v;
        }
        if (lane < 16) {                           // tail: f4 indices 256..271
            int p0 = (256 + lane) * 4;
            f32x4 v;
            #pragma unroll
            for (int e = 0; e < 4; ++e) {
                int p = p0 + e;
                int i = (int)((unsigned)p / 17u);
                int g = p - i * 17;
                int   g0 = s_g0[wave][i];
                float t  = s_t[wave][i];
                v[e] = (g == g0) ? (1.0f - t) : ((g == g0 + 1) ? t : 0.0f);
            }
            *(f32x4*)(brow + p0) = v;
        }
    }

    // ---- phase 3: edge outputs (float4) + per-row reduction ----
    // Lane layout: quarter iq = lane>>4 owns input i = ib+iq; o = (lane&15)*4.
    f32x4 acc = {0.f, 0.f, 0.f, 0.f};
    float* erow = edge + (size_t)b * (NIN * NOUT);
    const int iq = lane >> 4;
    const int o  = (lane & 15) * 4;
    #pragma unroll 4
    for (int ib = 0; ib < NIN; ib += 4) {
        int   i  = ib + iq;
        float sl = s_silu[wave][i];
        float t  = s_t[wave][i];
        int   g0 = s_g0[wave][i];
        f32x4 sc = *(const f32x4*)(scale + i * NOUT + o);
        f32x4 w0 = {0.f, 0.f, 0.f, 0.f};
        f32x4 w1 = {0.f, 0.f, 0.f, 0.f};
        if ((unsigned)g0       < (unsigned)NG) w0 = *(const f32x4*)(Wt + (i * NG + g0)     * NOUT + o);
        if ((unsigned)(g0 + 1) < (unsigned)NG) w1 = *(const f32x4*)(Wt + (i * NG + g0 + 1) * NOUT + o);
        float mt = 1.0f - t;
        f32x4 v = sl * sc + mt * w0 + t * w1;
        *(f32x4*)(erow + i * NOUT + o) = v;
        acc += v;
    }
    // sum across the 4 quarters (lanes differing in bits 4,5)
    #pragma unroll
    for (int e = 0; e < 4; ++e) {
        float a = acc[e];
        a += __shfl_xor(a, 16);
        a += __shfl_xor(a, 32);
        acc[e] = a;
    }
    if (lane < 16) {
        f32x4 bi = *(const f32x4*)(bias + lane * 4);
        f32x4 r = acc * 0.125f + bi;   // 1/sqrt(64) = 0.125 exact
        *(f32x4*)(out + (size_t)b * NOUT + lane * 4) = r;
    }
}

extern "C" void kernel_launch(void* const* d_in, const int* in_sizes, int n_in,
                              void* d_out, int out_size, void* d_ws, size_t ws_size,
                              hipStream_t stream) {
    const float* x     = (const float*)d_in[0];
    const float* scale = (const float*)d_in[1];
    const float* W     = (const float*)d_in[2];
    const float* bias  = (const float*)d_in[3];

    float* out   = (float*)d_out;
    float* edge  = out + OUT_ELEMS;
    float* basis = edge + EDGE_ELEMS;

    float* Wt = (float*)d_ws;
    const int n = NIN * NOUT * NG;
    if (ws_size >= WT_BYTES) {
        kan_transpose_w<<<(n + 255) / 256, 256, 0, stream>>>(W, Wt);
        kan_kernel<<<dim3(NBATCH / 4), dim3(256), 0, stream>>>(x, scale, Wt, bias, out, edge, basis);
    }
}